// Round 13
// baseline (20776.797 us; speedup 1.0000x reference)
//
#include <hip/hip_runtime.h>
#include <hip/hip_cooperative_groups.h>
#include <math.h>

namespace cgrp = cooperative_groups;

#define V 13000
#define D 300
#define M 500
#define B 64
#define NW 5
#define T 128
#define NSUP (B*NW)        // 320
#define NSEQ (NSUP + B)    // 384
#define CT 32              // chains per compute tile
#define NCT 12             // 384/32
#define MT 16              // m per block
#define KSPL 4             // K splits (one wave each)
#define CHK 20             // k per chunk
#define CKS 10             // chunks per split (4*10*20 = 800)
#define KROW 800           // act row: k<300 = x, k>=300 = c(m=k-300)
#define NSTEP (T-1)        // 127
#define ASTR 28            // LDS floats per A row (20 k + 8 pad)
#define APW (48*ASTR)      // 1344 floats per wave
#define SMSZ 6144          // max(4*1344=5376, red 4*16*3*32=6144)
#define NCOMP 768          // 12 ct * 2 dir * 32 mt  (= 256 CU * 3)

__device__ __forceinline__ float sigmoidf_(float x){ return 1.0f/(1.0f+expf(-x)); }

// ---- agent-scope (cross-XCD coherent) access helpers ----
__device__ __forceinline__ float2 ld2_agent(const float* p){
    unsigned long long u = __hip_atomic_load((unsigned long long*)p, __ATOMIC_RELAXED, __HIP_MEMORY_SCOPE_AGENT);
    union { unsigned long long u; float2 f; } c; c.u = u; return c.f;
}
__device__ __forceinline__ float ldf_agent(const float* p){
    unsigned u = __hip_atomic_load((unsigned*)p, __ATOMIC_RELAXED, __HIP_MEMORY_SCOPE_AGENT);
    union { unsigned u; float f; } c; c.u = u; return c.f;
}
__device__ __forceinline__ void stf_agent(float* p, float v){
    union { unsigned u; float f; } c; c.f = v;
    __hip_atomic_store((unsigned*)p, c.u, __ATOMIC_RELAXED, __HIP_MEMORY_SCOPE_AGENT);
}

// actB layout: actB[(d*KROW + k)*NSEQ + rank]
// c_final layout: c_final[(d*NSEQ + chain)*M + m]

__global__ void init_kernel(const float* __restrict__ c0L, const float* __restrict__ c0R,
                            float* __restrict__ actB0, float* __restrict__ c_final)
{
    int idx = blockIdx.x*256 + threadIdx.x;      // 2*M*NSEQ
    if (idx >= 2*M*NSEQ) return;
    int d = idx / (M*NSEQ);
    int rem = idx % (M*NSEQ);
    int m = rem / NSEQ;
    int r = rem % NSEQ;
    float v = d ? c0R[m] : c0L[m];
    actB0[((size_t)d*KROW + 300 + m)*NSEQ + r] = v;
    c_final[((size_t)d*NSEQ + r)*M + m] = v;
}

__global__ void sort_kernel(const int* __restrict__ blank_sup, const int* __restrict__ blank_tgt,
                            int* __restrict__ perm, int* __restrict__ lenR, int* __restrict__ tmax)
{
    __shared__ int L0[NSEQ], L1[NSEQ];
    int tid = threadIdx.x;                       // 384 threads
    int blank = (tid < NSUP) ? blank_sup[tid] : blank_tgt[tid - NSUP];
    int l0 = blank, l1 = (T-1) - blank;
    L0[tid] = l0; L1[tid] = l1;
    __syncthreads();
    int r0 = 0, r1 = 0;
    for (int j = 0; j < NSEQ; ++j) {
        int c = L0[j]; r0 += (c > l0) || (c == l0 && j < tid);
        int d = L1[j]; r1 += (d > l1) || (d == l1 && j < tid);
    }
    perm[r0] = tid;        lenR[r0] = l0;
    perm[NSEQ + r1] = tid; lenR[NSEQ + r1] = l1;
    __syncthreads();
    if (tid < 2*NCT) {
        int dir = tid / NCT, t = tid % NCT;
        tmax[tid] = lenR[dir*NSEQ + t*CT];       // descending -> first rank in tile is max
    }
}

// -------- persistent cooperative kernel: all 127 steps, one grid.sync per step --------
// block = (ct, dir, mt): 16m x 3g x 32c; 4 waves = K splits of 200 ticks.
// lane = ml(16) x cg(4); lane tile = 1m x 3g x 8c (24 acc).
// A (weights, read-only, plain/L2) via LDS; B (acts) agent 8-B loads, ring-4.
__global__ __launch_bounds__(256, 3)
void persist_kernel(float* __restrict__ b0buf, float* __restrict__ b1buf,
                    float* __restrict__ c_final,
                    const float* __restrict__ WL, const float* __restrict__ UL, const float* __restrict__ bL,
                    const float* __restrict__ WR, const float* __restrict__ UR, const float* __restrict__ bR,
                    const int* __restrict__ perm, const int* __restrict__ lenR, const int* __restrict__ tmax,
                    const int* __restrict__ sup_tok, const int* __restrict__ tgt_tok,
                    const float* __restrict__ emb)
{
    cgrp::grid_group grid = cgrp::this_grid();
    const int bid = blockIdx.x;
    const int tid = threadIdx.x;

    // bid = ct*64 + d*32 + mt  (blocks sharing weight panel (d,mt) share bid%8 -> XCD heuristic)
    const int ct = bid >> 6;
    const int dm = bid & 63;
    const int d  = dm >> 5;
    const int mt = dm & 31;
    const int dct = d*NCT + ct;
    const int rank0 = ct*CT;
    const int m0 = mt*MT;
    const int tmax_b = tmax[dct];

    __shared__ __align__(16) float smem[SMSZ];

    const int ks   = tid >> 6;
    const int lane = tid & 63;
    const int ml   = lane >> 2;
    const int cgx  = lane & 3;

    const float* Wd = d ? WR : WL;
    const float* Ud = d ? UR : UL;
    const float* bias = d ? bR : bL;

    float* As = smem + ks*APW;
    const float* Ard = As + ml*ASTR;

    // ---- hoisted A staging geometry (32-bit offsets; bases wave-uniform) ----
    int offW[4], offU[4], aDo[4];
    #pragma unroll
    for (int i = 0; i < 4; ++i) {
        int slot = lane + 64*i; if (slot >= 240) slot = 239;
        int row = slot/5, kq = slot%5;
        int g = row >> 4, mr = row & 15;
        int m = m0 + mr; if (m >= M) m = M-1;
        offW[i] = (g*M + m)*D + kq*4;
        offU[i] = (g*M + m)*M + kq*4;
        aDo[i]  = row*ASTR + kq*4;
    }
    const bool a3 = (lane < 48);

    // ---- hoisted update-cell geometry (2 cells per thread) ----
    int   up_len[2], up_m[2]; size_t up_ci[2], up_cf[2]; bool up_v[2];
    float up_bf[2], up_bi[2], up_bc[2];
    #pragma unroll
    for (int q = 0; q < 2; ++q) {
        int cell = tid*2 + q;
        int mr = cell >> 5, c = cell & 31;
        int m = m0 + mr;
        up_v[q] = (m < M);
        int mm = up_v[q] ? m : M-1;
        int rank = rank0 + c;
        up_m[q]   = mr;
        up_len[q] = lenR[d*NSEQ + rank];
        up_ci[q]  = ((size_t)d*KROW + 300 + mm)*NSEQ + rank;
        up_cf[q]  = ((size_t)d*NSEQ + perm[d*NSEQ + rank])*M + mm;
        up_bf[q] = bias[mm]; up_bi[q] = bias[M + mm]; up_bc[q] = bias[2*M + mm];
    }

    // ---- hoisted gather geometry: block covers (d, ranks rank0..+32, k in [mt*10, mt*10+10)) ----
    const int gk0 = mt*10;
    const int gr  = tid & 31;
    const int gkl = tid >> 5;                    // 0..7
    const int grank = rank0 + gr;
    const int glen  = lenR[d*NSEQ + grank];
    const int gch   = perm[d*NSEQ + grank];

    auto gatherX = [&](int sn, float* dst){
        if (sn >= NSTEP || gk0 >= D) return;
        if (sn < glen) {
            const int tpos = d ? (T-1 - sn) : sn;
            const int tok = (gch < NSUP) ? sup_tok[gch*T + tpos] : tgt_tok[(gch-NSUP)*T + tpos];
            const float* src = emb + (size_t)tok*D;
            int k = gk0 + gkl;
            stf_agent(dst + ((size_t)d*KROW + k)*NSEQ + grank, src[k]);
            if (gkl < 2) {
                int k2 = gk0 + 8 + gkl;
                stf_agent(dst + ((size_t)d*KROW + k2)*NSEQ + grank, src[k2]);
            }
        }
    };

    float4 aR4[4];
    auto ldA = [&](int ck){
        const int gc = ks*CKS + ck;
        const bool isx = (gc < 15);
        const int koff = isx ? gc*CHK : gc*CHK - 300;
        const float* base = isx ? Wd : Ud;
        aR4[0] = *(const float4*)(base + (isx ? offW[0] : offU[0]) + koff);
        aR4[1] = *(const float4*)(base + (isx ? offW[1] : offU[1]) + koff);
        aR4[2] = *(const float4*)(base + (isx ? offW[2] : offU[2]) + koff);
        if (a3) aR4[3] = *(const float4*)(base + (isx ? offW[3] : offU[3]) + koff);
    };
    auto wrA = [&](){
        *(float4*)(As + aDo[0]) = aR4[0];
        *(float4*)(As + aDo[1]) = aR4[1];
        *(float4*)(As + aDo[2]) = aR4[2];
        if (a3) *(float4*)(As + aDo[3]) = aR4[3];
    };

    // ================= prologue: x for step 0 =================
    gatherX(0, b0buf);
    grid.sync();

    for (int s = 0; s < NSTEP; ++s) {
        const float* cur = (s & 1) ? b1buf : b0buf;
        float*       nxt = (s & 1) ? b0buf : b1buf;

        if (s < tmax_b) {
            float2 acc[3][4];
            #pragma unroll
            for (int g = 0; g < 3; ++g)
                #pragma unroll
                for (int j = 0; j < 4; ++j) acc[g][j] = make_float2(0.f, 0.f);

            const float* bq = cur + ((size_t)d*KROW + ks*200)*NSEQ + rank0 + cgx*8;
            float2 ring[4][4];
            #pragma unroll
            for (int q = 0; q < 4; ++q) {
                const float* p = bq + (size_t)q*NSEQ;
                ring[q][0] = ld2_agent(p);     ring[q][1] = ld2_agent(p + 2);
                ring[q][2] = ld2_agent(p + 4); ring[q][3] = ld2_agent(p + 6);
            }
            const float* bp4 = bq + (size_t)4*NSEQ;

            ldA(0);
            for (int ck = 0; ck < CKS; ++ck) {
                wrA();                           // per-wave DS in-order
                if (ck + 1 < CKS) ldA(ck + 1);
                #pragma unroll
                for (int t2 = 0; t2 < 10; ++t2) {
                    const int kk = t2*2;
                    float2 a0 = *(const float2*)(Ard + kk);
                    float2 a1 = *(const float2*)(Ard + 16*ASTR + kk);
                    float2 a2 = *(const float2*)(Ard + 32*ASTR + kk);
                    #pragma unroll
                    for (int sub = 0; sub < 2; ++sub) {
                        const int sl = (kk + sub) & 3;   // static
                        float2 bv0 = ring[sl][0], bv1 = ring[sl][1];
                        float2 bv2 = ring[sl][2], bv3 = ring[sl][3];
                        // refill slot for tick +4 (may over-read <=4 rows past stripe: discarded)
                        ring[sl][0] = ld2_agent(bp4);     ring[sl][1] = ld2_agent(bp4 + 2);
                        ring[sl][2] = ld2_agent(bp4 + 4); ring[sl][3] = ld2_agent(bp4 + 6);
                        bp4 += NSEQ;
                        float ax0 = sub ? a0.y : a0.x;
                        float ax1 = sub ? a1.y : a1.x;
                        float ax2 = sub ? a2.y : a2.x;
#define FMA2(AC, AV, BV) AC.x += (AV)*(BV).x; AC.y += (AV)*(BV).y;
                        FMA2(acc[0][0], ax0, bv0) FMA2(acc[0][1], ax0, bv1)
                        FMA2(acc[0][2], ax0, bv2) FMA2(acc[0][3], ax0, bv3)
                        FMA2(acc[1][0], ax1, bv0) FMA2(acc[1][1], ax1, bv1)
                        FMA2(acc[1][2], ax1, bv2) FMA2(acc[1][3], ax1, bv3)
                        FMA2(acc[2][0], ax2, bv0) FMA2(acc[2][1], ax2, bv1)
                        FMA2(acc[2][2], ax2, bv2) FMA2(acc[2][3], ax2, bv3)
#undef FMA2
                    }
                }
            }

            // ---- cross-split reduction through LDS ----
            __syncthreads();
            float* red = smem;
            #pragma unroll
            for (int g = 0; g < 3; ++g)
                #pragma unroll
                for (int j = 0; j < 4; ++j)
                    *(float2*)&red[((ks*MT + ml)*3 + g)*CT + cgx*8 + j*2] = acc[g][j];
            __syncthreads();

            // ---- cell update (2 cells per thread) ----
            #pragma unroll
            for (int q = 0; q < 2; ++q) {
                if (up_v[q]) {
                    int mr = up_m[q], c = (tid*2 + q) & 31;
                    float g0 = up_bf[q], g1 = up_bi[q], g2 = up_bc[q];
                    #pragma unroll
                    for (int kq = 0; kq < KSPL; ++kq) {
                        g0 += red[((kq*MT + mr)*3 + 0)*CT + c];
                        g1 += red[((kq*MT + mr)*3 + 1)*CT + c];
                        g2 += red[((kq*MT + mr)*3 + 2)*CT + c];
                    }
                    float cold = ldf_agent(cur + up_ci[q]);
                    float f  = sigmoidf_(g0);
                    float i2 = sigmoidf_(g1);
                    float cb = tanhf(g2);
                    float cn = (s < up_len[q]) ? (f*cold + i2*cb) : cold;
                    stf_agent(nxt + up_ci[q], cn);
                    if (s == up_len[q] - 1) c_final[up_cf[q]] = cn;
                }
            }
        }

        gatherX(s + 1, nxt);
        grid.sync();
    }
}

// ---- r12-style per-step fallback (used only if cooperative launch fails) ----
__global__ __launch_bounds__(256, 3)
void step_fallback(int s,
                   const float* __restrict__ actB_cur, float* __restrict__ actB_next,
                   float* __restrict__ c_final,
                   const float* __restrict__ WL, const float* __restrict__ UL, const float* __restrict__ bL,
                   const float* __restrict__ WR, const float* __restrict__ UR, const float* __restrict__ bR,
                   const int* __restrict__ perm, const int* __restrict__ lenR, const int* __restrict__ tmax,
                   const int* __restrict__ sup_tok, const int* __restrict__ tgt_tok,
                   const float* __restrict__ emb)
{
    const int bid = blockIdx.x;
    const int tid = threadIdx.x;
    const int ct = bid >> 6;
    const int dm = bid & 63;
    const int d  = dm >> 5;
    const int mt = dm & 31;
    const int rank0 = ct*CT;
    const int m0 = mt*MT;

    // gather x for step s+1 (each block its own (ct, k-slice), coalesced)
    {
        const int gk0 = mt*10;
        const int gr  = tid & 31;
        const int gkl = tid >> 5;
        const int sn = s + 1;
        if (sn < NSTEP && gk0 < D) {
            const int grank = rank0 + gr;
            if (sn < lenR[d*NSEQ + grank]) {
                const int gch = perm[d*NSEQ + grank];
                const int tpos = d ? (T-1 - sn) : sn;
                const int tok = (gch < NSUP) ? sup_tok[gch*T + tpos] : tgt_tok[(gch-NSUP)*T + tpos];
                const float* src = emb + (size_t)tok*D;
                actB_next[((size_t)d*KROW + gk0 + gkl)*NSEQ + grank] = src[gk0 + gkl];
                if (gkl < 2)
                    actB_next[((size_t)d*KROW + gk0 + 8 + gkl)*NSEQ + grank] = src[gk0 + 8 + gkl];
            }
        }
    }
    if (s < 0 || s >= tmax[d*NCT + ct]) return;

    __shared__ __align__(16) float smem[SMSZ];
    const int ks   = tid >> 6;
    const int lane = tid & 63;
    const int ml   = lane >> 2;
    const int cgx  = lane & 3;
    const float* Wd = d ? WR : WL;
    const float* Ud = d ? UR : UL;
    const float* bias = d ? bR : bL;
    float* As = smem + ks*APW;
    const float* Ard = As + ml*ASTR;

    int offW[4], offU[4], aDo[4];
    #pragma unroll
    for (int i = 0; i < 4; ++i) {
        int slot = lane + 64*i; if (slot >= 240) slot = 239;
        int row = slot/5, kq = slot%5;
        int g = row >> 4, mr = row & 15;
        int m = m0 + mr; if (m >= M) m = M-1;
        offW[i] = (g*M + m)*D + kq*4;
        offU[i] = (g*M + m)*M + kq*4;
        aDo[i]  = row*ASTR + kq*4;
    }
    const bool a3 = (lane < 48);
    float4 aR4[4];
    auto ldA = [&](int ck){
        const int gc = ks*CKS + ck;
        const bool isx = (gc < 15);
        const int koff = isx ? gc*CHK : gc*CHK - 300;
        const float* base = isx ? Wd : Ud;
        aR4[0] = *(const float4*)(base + (isx ? offW[0] : offU[0]) + koff);
        aR4[1] = *(const float4*)(base + (isx ? offW[1] : offU[1]) + koff);
        aR4[2] = *(const float4*)(base + (isx ? offW[2] : offU[2]) + koff);
        if (a3) aR4[3] = *(const float4*)(base + (isx ? offW[3] : offU[3]) + koff);
    };
    auto wrA = [&](){
        *(float4*)(As + aDo[0]) = aR4[0];
        *(float4*)(As + aDo[1]) = aR4[1];
        *(float4*)(As + aDo[2]) = aR4[2];
        if (a3) *(float4*)(As + aDo[3]) = aR4[3];
    };

    float2 acc[3][4];
    #pragma unroll
    for (int g = 0; g < 3; ++g)
        #pragma unroll
        for (int j = 0; j < 4; ++j) acc[g][j] = make_float2(0.f, 0.f);

    const float* bq = actB_cur + ((size_t)d*KROW + ks*200)*NSEQ + rank0 + cgx*8;
    float2 ring[4][4];
    #pragma unroll
    for (int q = 0; q < 4; ++q) {
        const float* p = bq + (size_t)q*NSEQ;
        ring[q][0] = *(const float2*)p;     ring[q][1] = *(const float2*)(p + 2);
        ring[q][2] = *(const float2*)(p + 4); ring[q][3] = *(const float2*)(p + 6);
    }
    const float* bp4 = bq + (size_t)4*NSEQ;

    ldA(0);
    for (int ck = 0; ck < CKS; ++ck) {
        wrA();
        if (ck + 1 < CKS) ldA(ck + 1);
        #pragma unroll
        for (int t2 = 0; t2 < 10; ++t2) {
            const int kk = t2*2;
            float2 a0 = *(const float2*)(Ard + kk);
            float2 a1 = *(const float2*)(Ard + 16*ASTR + kk);
            float2 a2 = *(const float2*)(Ard + 32*ASTR + kk);
            #pragma unroll
            for (int sub = 0; sub < 2; ++sub) {
                const int sl = (kk + sub) & 3;
                float2 bv0 = ring[sl][0], bv1 = ring[sl][1];
                float2 bv2 = ring[sl][2], bv3 = ring[sl][3];
                ring[sl][0] = *(const float2*)bp4;     ring[sl][1] = *(const float2*)(bp4 + 2);
                ring[sl][2] = *(const float2*)(bp4 + 4); ring[sl][3] = *(const float2*)(bp4 + 6);
                bp4 += NSEQ;
                float ax0 = sub ? a0.y : a0.x;
                float ax1 = sub ? a1.y : a1.x;
                float ax2 = sub ? a2.y : a2.x;
#define FMA2(AC, AV, BV) AC.x += (AV)*(BV).x; AC.y += (AV)*(BV).y;
                FMA2(acc[0][0], ax0, bv0) FMA2(acc[0][1], ax0, bv1)
                FMA2(acc[0][2], ax0, bv2) FMA2(acc[0][3], ax0, bv3)
                FMA2(acc[1][0], ax1, bv0) FMA2(acc[1][1], ax1, bv1)
                FMA2(acc[1][2], ax1, bv2) FMA2(acc[1][3], ax1, bv3)
                FMA2(acc[2][0], ax2, bv0) FMA2(acc[2][1], ax2, bv1)
                FMA2(acc[2][2], ax2, bv2) FMA2(acc[2][3], ax2, bv3)
#undef FMA2
            }
        }
    }

    __syncthreads();
    float* red = smem;
    #pragma unroll
    for (int g = 0; g < 3; ++g)
        #pragma unroll
        for (int j = 0; j < 4; ++j)
            *(float2*)&red[((ks*MT + ml)*3 + g)*CT + cgx*8 + j*2] = acc[g][j];
    __syncthreads();

    #pragma unroll
    for (int q = 0; q < 2; ++q) {
        int cell = tid*2 + q;
        int mr = cell >> 5, c = cell & 31;
        int m = m0 + mr;
        if (m < M) {
            float g0 = bias[m], g1 = bias[M + m], g2 = bias[2*M + m];
            #pragma unroll
            for (int kq = 0; kq < KSPL; ++kq) {
                g0 += red[((kq*MT + mr)*3 + 0)*CT + c];
                g1 += red[((kq*MT + mr)*3 + 1)*CT + c];
                g2 += red[((kq*MT + mr)*3 + 2)*CT + c];
            }
            int rank = rank0 + c;
            int len  = lenR[d*NSEQ + rank];
            size_t cidx = ((size_t)d*KROW + 300 + m)*NSEQ + rank;
            float cold = actB_cur[cidx];
            float f  = sigmoidf_(g0);
            float i2 = sigmoidf_(g1);
            float cb = tanhf(g2);
            float cn = (s < len) ? (f*cold + i2*cb) : cold;
            actB_next[cidx] = cn;
            if (s == len - 1) {
                int ch = perm[d*NSEQ + rank];
                c_final[((size_t)d*NSEQ + ch)*M + m] = cn;
            }
        }
    }
}

__global__ void env_kernel(const float* __restrict__ l_states, const float* __restrict__ r_states,
                           const float* __restrict__ Wo, const float* __restrict__ Uo,
                           const float* __restrict__ bo,
                           float* __restrict__ env)
{
    __shared__ __align__(16) float l[M];
    __shared__ __align__(16) float r[M];
    const int i = blockIdx.x;
    const int tid = threadIdx.x;
    for (int m=tid; m<M; m+=blockDim.x){ l[m]=l_states[i*M+m]; r[m]=r_states[i*M+m]; }
    __syncthreads();
    for (int d=tid; d<D; d+=blockDim.x) {
        const float4* wo = reinterpret_cast<const float4*>(Wo + (size_t)d*M);
        const float4* uo = reinterpret_cast<const float4*>(Uo + (size_t)d*M);
        const float4* lv = reinterpret_cast<const float4*>(l);
        const float4* rv = reinterpret_cast<const float4*>(r);
        float acc = bo[d];
        #pragma unroll 5
        for (int q=0; q<M/4; ++q) {
            float4 a=wo[q], bv=lv[q], u=uo[q], rr=rv[q];
            acc += a.x*bv.x + a.y*bv.y + a.z*bv.z + a.w*bv.w;
            acc += u.x*rr.x + u.y*rr.y + u.z*rr.z + u.w*rr.w;
        }
        env[i*D + d] = tanhf(acc);
    }
}

__global__ void episode_kernel(const float* __restrict__ env, const int* __restrict__ target_y,
                               float* __restrict__ flags, float* __restrict__ losses)
{
    const int b = blockIdx.x;
    const int lane = threadIdx.x;
    const float* tgt = env + (size_t)(NSUP + b)*D;

    float tn = 0.f;
    for (int d=lane; d<D; d+=64){ float v=tgt[d]; tn += v*v; }
    for (int off=32; off; off>>=1) tn += __shfl_down(tn, off);
    tn = __shfl(tn, 0);

    float z[NW];
    for (int n=0; n<NW; ++n){
        const float* sup = env + (size_t)(b*NW + n)*D;
        float dot=0.f, sn=0.f;
        for (int d=lane; d<D; d+=64){ float sv=sup[d], tv=tgt[d]; dot+=sv*tv; sn+=sv*sv; }
        for (int off=32; off; off>>=1){ dot += __shfl_down(dot,off); sn += __shfl_down(sn,off); }
        dot = __shfl(dot,0); sn = __shfl(sn,0);
        float denom = fmaxf(sqrtf(sn)*sqrtf(tn), 1e-8f);
        z[n] = dot/denom*10.0f;
    }

    if (lane==0){
        float mx=z[0];
        for(int n=1;n<NW;n++) mx=fmaxf(mx,z[n]);
        float se=0.f; float p[NW];
        for(int n=0;n<NW;n++){ p[n]=expf(z[n]-mx); se+=p[n]; }
        for(int n=0;n<NW;n++) p[n]/=se;
        int am=0; float bv=p[0];
        for(int n=1;n<NW;n++) if(p[n]>bv){bv=p[n];am=n;}
        int y = target_y[b];
        flags[b] = (am==y)?1.0f:0.0f;
        float mx2=p[0]; for(int n=1;n<NW;n++) mx2=fmaxf(mx2,p[n]);
        float se2=0.f; for(int n=0;n<NW;n++) se2+=expf(p[n]-mx2);
        losses[b] = -(p[y]-mx2-logf(se2));
    }
}

__global__ void finalize_kernel(const float* __restrict__ flags, const float* __restrict__ losses,
                                float* __restrict__ out)
{
    const int lane = threadIdx.x; // 64 threads
    float f = flags[lane], l = losses[lane];
    for (int off=32; off; off>>=1){ f += __shfl_down(f,off); l += __shfl_down(l,off); }
    if (lane==0){ out[0] = f/(float)B; out[1] = l/(float)B; }
}

extern "C" void kernel_launch(void* const* d_in, const int* in_sizes, int n_in,
                              void* d_out, int out_size, void* d_ws, size_t ws_size,
                              hipStream_t stream) {
    const int*   sup_tok   = (const int*)d_in[0];
    const int*   tgt_tok   = (const int*)d_in[1];
    const int*   blank_sup = (const int*)d_in[2];
    const int*   blank_tgt = (const int*)d_in[3];
    const int*   target_y  = (const int*)d_in[4];
    const float* emb = (const float*)d_in[5];
    const float* WL  = (const float*)d_in[6];
    const float* UL  = (const float*)d_in[7];
    const float* bL  = (const float*)d_in[8];
    const float* WR  = (const float*)d_in[9];
    const float* UR  = (const float*)d_in[10];
    const float* bR  = (const float*)d_in[11];
    const float* Wo  = (const float*)d_in[12];
    const float* Uo  = (const float*)d_in[13];
    const float* bo  = (const float*)d_in[14];
    const float* c0L = (const float*)d_in[15];
    const float* c0R = (const float*)d_in[16];

    const size_t ACTSZ = (size_t)2*KROW*NSEQ;           // 614400 floats
    float* ws_f = (float*)d_ws;
    float* actB0   = ws_f;
    float* actB1   = actB0 + ACTSZ;
    float* c_final = actB1 + ACTSZ;                     // [2*384*500]
    float* env     = c_final + 2*NSEQ*M;                // [384*300]
    float* flags   = env + NSEQ*D;                      // [64]
    float* losses  = flags + B;                         // [64]
    int*   perm    = (int*)(losses + B);                // [2*384]
    int*   lenR    = perm + 2*NSEQ;                     // [2*384]
    int*   tmax    = lenR + 2*NSEQ;                     // [24]

    init_kernel<<<(2*M*NSEQ + 255)/256, 256, 0, stream>>>(c0L, c0R, actB0, c_final);
    sort_kernel<<<1, NSEQ, 0, stream>>>(blank_sup, blank_tgt, perm, lenR, tmax);

    void* kargs[] = { (void*)&actB0, (void*)&actB1, (void*)&c_final,
                      (void*)&WL, (void*)&UL, (void*)&bL,
                      (void*)&WR, (void*)&UR, (void*)&bR,
                      (void*)&perm, (void*)&lenR, (void*)&tmax,
                      (void*)&sup_tok, (void*)&tgt_tok, (void*)&emb };
    hipError_t ce = hipLaunchCooperativeKernel((const void*)persist_kernel,
                                               dim3(NCOMP), dim3(256), kargs, 0, stream);
    if (ce != hipSuccess) {
        (void)hipGetLastError();
        // fallback: per-step launches (r12-proven structure)
        step_fallback<<<NCOMP, 256, 0, stream>>>(-1, actB1, actB0, c_final,
                                                 WL, UL, bL, WR, UR, bR,
                                                 perm, lenR, tmax, sup_tok, tgt_tok, emb);
        for (int s = 0; s < NSTEP; ++s) {
            float* cur  = (s & 1) ? actB1 : actB0;
            float* next = (s & 1) ? actB0 : actB1;
            step_fallback<<<NCOMP, 256, 0, stream>>>(s, cur, next, c_final,
                                                     WL, UL, bL, WR, UR, bR,
                                                     perm, lenR, tmax, sup_tok, tgt_tok, emb);
        }
    }

    env_kernel<<<NSEQ, 256, 0, stream>>>(c_final, c_final + NSEQ*M, Wo, Uo, bo, env);
    episode_kernel<<<B, 64, 0, stream>>>(env, target_y, flags, losses);
    finalize_kernel<<<1, 64, 0, stream>>>(flags, losses, (float*)d_out);
}

// Round 16
// 5315.340 us; speedup vs baseline: 3.9088x; 3.9088x over previous
//
#include <hip/hip_runtime.h>
#include <math.h>

#define V 13000
#define D 300
#define M 500
#define B 64
#define NW 5
#define T 128
#define NSUP (B*NW)        // 320
#define NSEQ (NSUP + B)    // 384
#define CT 48              // chains per compute tile
#define NCT 8              // 384/48
#define MT 16              // m per block
#define NMT 32
#define KROW 800           // act row: k<300 = x, k>=300 = c(m=k-300)
#define NSTEP (T-1)        // 127
#define NST 8              // K stripes of 100 (4 waves x 2 lane-halves)
#define CHK 10             // k per chunk
#define NCK 10             // chunks per stripe
#define ASTR 68            // A LDS k-row stride (64 cols + 4 pad); col = ml*4 + g
#define APS 684            // A floats per stripe (10*68 + 4 bank-skew)
#define BSTR 48            // B LDS k-row stride (48 chains)
#define BPS 480            // 10*48
#define AREG 0
#define BREG (NST*APS)     // 5472
#define SMSZ (BREG + NST*BPS)  // 9312 floats (>= red 4*16*3*48 = 9216)
#define NCOMP 512          // 8 ct * 2 dir * 32 mt = 2 blocks/CU exactly
#define NGATH 12           // 2 dir * 6 rank-tiles of 64

__device__ __forceinline__ float sigmoidf_(float x){ return 1.0f/(1.0f+expf(-x)); }

// actB layout: actB[(d*KROW + k)*NSEQ + rank]
// c_final layout: c_final[(d*NSEQ + chain)*M + m]

__global__ void init_kernel(const float* __restrict__ c0L, const float* __restrict__ c0R,
                            float* __restrict__ actB0, float* __restrict__ c_final)
{
    int idx = blockIdx.x*256 + threadIdx.x;      // 2*M*NSEQ
    if (idx >= 2*M*NSEQ) return;
    int d = idx / (M*NSEQ);
    int rem = idx % (M*NSEQ);
    int m = rem / NSEQ;
    int r = rem % NSEQ;
    float v = d ? c0R[m] : c0L[m];
    actB0[((size_t)d*KROW + 300 + m)*NSEQ + r] = v;
    c_final[((size_t)d*NSEQ + r)*M + m] = v;
}

__global__ void sort_kernel(const int* __restrict__ blank_sup, const int* __restrict__ blank_tgt,
                            int* __restrict__ perm, int* __restrict__ lenR, int* __restrict__ tmax)
{
    __shared__ int L0[NSEQ], L1[NSEQ];
    int tid = threadIdx.x;                       // 384 threads
    int blank = (tid < NSUP) ? blank_sup[tid] : blank_tgt[tid - NSUP];
    int l0 = blank, l1 = (T-1) - blank;
    L0[tid] = l0; L1[tid] = l1;
    __syncthreads();
    int r0 = 0, r1 = 0;
    for (int j = 0; j < NSEQ; ++j) {
        int c = L0[j]; r0 += (c > l0) || (c == l0 && j < tid);
        int d = L1[j]; r1 += (d > l1) || (d == l1 && j < tid);
    }
    perm[r0] = tid;        lenR[r0] = l0;
    perm[NSEQ + r1] = tid; lenR[NSEQ + r1] = l1;
    __syncthreads();
    if (tid < 2*NCT) {
        int dir = tid / NCT, t = tid % NCT;
        tmax[tid] = lenR[dir*NSEQ + t*CT];       // descending -> first rank in tile is max
    }
}

// -------- fused per-step kernel: 512 compute blocks + 12 gather blocks --------
// compute block = (ct, dir, mt): 16m x 3g x 48c; 4 waves x 2 lane-halves = 8 K-stripes of 100.
// lane = half(2) x ty(8: m-pair) x tx(4: 12-chain group); lane tile = 2m x 3g x 12c (72 acc).
__global__ __launch_bounds__(256, 2)
void step_kernel(int s,
                 const float* __restrict__ actB_cur, float* __restrict__ actB_next,
                 float* __restrict__ c_final,
                 const float* __restrict__ WL, const float* __restrict__ UL, const float* __restrict__ bL,
                 const float* __restrict__ WR, const float* __restrict__ UR, const float* __restrict__ bR,
                 const int* __restrict__ perm, const int* __restrict__ lenR, const int* __restrict__ tmax,
                 const int* __restrict__ sup_tok, const int* __restrict__ tgt_tok,
                 const float* __restrict__ emb)
{
    const int bid = blockIdx.x;
    const int tid = threadIdx.x;

    if (bid >= NCOMP) {
        // ---- gather x for step s+1 into actB_next (coalesced: lane = rank) ----
        const int gb = bid - NCOMP;              // 0..11
        const int d  = gb / 6;
        const int rt = gb % 6;                   // 64-rank tile
        const int sn = s + 1;
        if (sn >= NSTEP) return;
        const int rr = tid & 63;
        const int kk = tid >> 6;                 // 0..3
        const int rank = rt*64 + rr;
        if (sn >= lenR[d*NSEQ + rank]) return;   // frozen chain: x never used again
        const int ch = perm[d*NSEQ + rank];
        const int tpos = d ? (T-1 - sn) : sn;
        const int tok = (ch < NSUP) ? sup_tok[ch*T + tpos] : tgt_tok[(ch-NSUP)*T + tpos];
        const float* src = emb + (size_t)tok*D + kk;
        float* dst = actB_next + (size_t)d*KROW*NSEQ + rank;
        #pragma unroll 5
        for (int k4 = 0; k4 < 75; ++k4)
            dst[(size_t)(k4*4 + kk)*NSEQ] = src[k4*4];
        return;
    }
    if (s < 0) return;

    // bid = ct*64 + d*32 + mt -> blocks sharing weight panel (d,mt) share bid%8 (XCD)
    const int ct = bid >> 6;                     // 0..7
    const int dm = bid & 63;
    const int d  = dm >> 5;
    const int mt = dm & 31;
    if (s >= tmax[d*NCT + ct]) return;

    __shared__ __align__(16) float smem[SMSZ];

    const int ks   = tid >> 6;                   // wave
    const int lane = tid & 63;
    const int half = lane >> 5;                  // K-stripe half
    const int l32  = lane & 31;
    const int ty   = l32 >> 2;                   // 0..7: m-pair
    const int tx   = l32 & 3;                    // 0..3: 12-chain group
    const int rank0 = ct*CT;
    const int m0 = mt*MT;
    const int mystripe = ks*2 + half;

    const float* Wd = d ? WR : WL;
    const float* Ud = d ? UR : UL;
    const float* bias = d ? bR : bL;

    // ---- hoisted A staging: 480 f2 slots = 2 stripes x 48 rows x 5 kq ----
    // LDS layout [k][col] with col = ml*4 + g  (read expects {g0,g1,g2,pad} per m)
    int aOffW[8], aOffU[8], aLds[8], aKb[8];
    #pragma unroll
    for (int i = 0; i < 8; ++i) {
        int slot = lane + 64*i; if (slot >= 480) slot = 479;
        int st2 = slot/240;
        int r   = slot%240;
        int row = r/5, kq = r%5;
        int g = row >> 4, ml = row & 15;
        int m = m0 + ml; if (m >= M) m = M-1;    // clamp (update discards)
        int stripe = ks*2 + st2;
        aKb[i]   = stripe*100 + kq*2;            // k at chunk 0
        aOffW[i] = (g*M + m)*D;
        aOffU[i] = (g*M + m)*M - 300;
        aLds[i]  = AREG + stripe*APS + (kq*2)*ASTR + (ml*4 + g);
    }
    const bool a7 = (lane + 64*7 < 480);

    // ---- hoisted B staging: 240 f4 slots = 2 stripes x 10 kk x 12 c4 ----
    // FIXED: include the d*KROW term (r14/r15 read dir-0 acts for dir-1 blocks)
    int bOff[4], bLds[4];
    #pragma unroll
    for (int i = 0; i < 4; ++i) {
        int slot = lane + 64*i; if (slot >= 240) slot = 239;
        int st2 = slot/120;
        int r   = slot%120;
        int kk = r/12, c4 = r%12;
        int stripe = ks*2 + st2;
        bOff[i] = (d*KROW + stripe*100 + kk)*NSEQ + rank0 + c4*4;   // FIXED
        bLds[i] = BREG + stripe*BPS + kk*BSTR + c4*4;
    }
    const bool b3 = (lane + 64*3 < 240);

    float2 aR[8]; float4 bRg[4];
    auto ldA = [&](int ck){
        #pragma unroll
        for (int i = 0; i < 8; ++i) {
            if (i == 7 && !a7) break;
            int kg = aKb[i] + ck*CHK;
            const float* p = (kg < 300) ? (Wd + aOffW[i] + kg) : (Ud + aOffU[i] + kg);
            aR[i] = *(const float2*)p;
        }
    };
    auto ldB = [&](int ck){
        const size_t o = (size_t)(ck*CHK)*NSEQ;
        #pragma unroll
        for (int i = 0; i < 4; ++i) {
            if (i == 3 && !b3) break;
            bRg[i] = *(const float4*)(actB_cur + bOff[i] + o);
        }
    };
    auto wrAB = [&](){
        #pragma unroll
        for (int i = 0; i < 8; ++i) {
            if (i == 7 && !a7) break;
            smem[aLds[i]]        = aR[i].x;
            smem[aLds[i] + ASTR] = aR[i].y;
        }
        #pragma unroll
        for (int i = 0; i < 4; ++i) {
            if (i == 3 && !b3) break;
            *(float4*)&smem[bLds[i]] = bRg[i];
        }
    };

    float4 acc[2][3][3];
    #pragma unroll
    for (int j = 0; j < 2; ++j)
        #pragma unroll
        for (int g = 0; g < 3; ++g)
            #pragma unroll
            for (int q = 0; q < 3; ++q) acc[j][g][q] = make_float4(0.f,0.f,0.f,0.f);

    const int Ab = AREG + mystripe*APS + ty*8;   // cols ml=2ty (+4 for 2ty+1)
    const int Bb = BREG + mystripe*BPS + tx*12;

#define FMA12(ACJG, AV, B0, B1, B2) \
    ACJG[0].x += (AV)*(B0).x; ACJG[0].y += (AV)*(B0).y; ACJG[0].z += (AV)*(B0).z; ACJG[0].w += (AV)*(B0).w; \
    ACJG[1].x += (AV)*(B1).x; ACJG[1].y += (AV)*(B1).y; ACJG[1].z += (AV)*(B1).z; ACJG[1].w += (AV)*(B1).w; \
    ACJG[2].x += (AV)*(B2).x; ACJG[2].y += (AV)*(B2).y; ACJG[2].z += (AV)*(B2).z; ACJG[2].w += (AV)*(B2).w;

    ldA(0); ldB(0);
    for (int ck = 0; ck < NCK; ++ck) {
        wrAB();                                  // per-wave DS in-order: reads below see these
        if (ck + 1 < NCK) { ldA(ck+1); ldB(ck+1); }
        #pragma unroll
        for (int kk = 0; kk < CHK; ++kk) {
            float4 a0 = *(const float4*)&smem[Ab + kk*ASTR];       // m=2ty:   {g0,g1,g2,pad}
            float4 a1 = *(const float4*)&smem[Ab + kk*ASTR + 4];   // m=2ty+1
            float4 b0 = *(const float4*)&smem[Bb + kk*BSTR];
            float4 b1 = *(const float4*)&smem[Bb + kk*BSTR + 4];
            float4 b2 = *(const float4*)&smem[Bb + kk*BSTR + 8];
            FMA12(acc[0][0], a0.x, b0, b1, b2);
            FMA12(acc[0][1], a0.y, b0, b1, b2);
            FMA12(acc[0][2], a0.z, b0, b1, b2);
            FMA12(acc[1][0], a1.x, b0, b1, b2);
            FMA12(acc[1][1], a1.y, b0, b1, b2);
            FMA12(acc[1][2], a1.z, b0, b1, b2);
        }
    }
#undef FMA12

    // ---- combine the two lane-halves (same cells, different K) in-register ----
    #pragma unroll
    for (int j = 0; j < 2; ++j)
        #pragma unroll
        for (int g = 0; g < 3; ++g)
            #pragma unroll
            for (int q = 0; q < 3; ++q) {
                float4 v = acc[j][g][q];
                v.x += __shfl_xor(v.x, 32);
                v.y += __shfl_xor(v.y, 32);
                v.z += __shfl_xor(v.z, 32);
                v.w += __shfl_xor(v.w, 32);
                acc[j][g][q] = v;
            }

    // ---- cross-wave reduction through LDS (reuse smem: [4][16][3][48] = 9216) ----
    __syncthreads();
    float* red = smem;
    if (half == 0) {
        #pragma unroll
        for (int j = 0; j < 2; ++j)
            #pragma unroll
            for (int g = 0; g < 3; ++g)
                #pragma unroll
                for (int q = 0; q < 3; ++q)
                    *(float4*)&red[((ks*MT + ty*2 + j)*3 + g)*CT + tx*12 + q*4] = acc[j][g][q];
    }
    __syncthreads();

    // ---- final: sum waves + bias, gates, cell update (3 cells per thread) ----
    #pragma unroll
    for (int q = 0; q < 3; ++q) {
        int cell = q*256 + tid;                  // 768 = 16 mr x 48 c
        int mr = cell / CT, c = cell % CT;
        int m = m0 + mr;
        if (m < M) {
            float g0 = bias[m], g1 = bias[M + m], g2 = bias[2*M + m];
            #pragma unroll
            for (int kq = 0; kq < 4; ++kq) {
                g0 += red[((kq*MT + mr)*3 + 0)*CT + c];
                g1 += red[((kq*MT + mr)*3 + 1)*CT + c];
                g2 += red[((kq*MT + mr)*3 + 2)*CT + c];
            }
            int rank = rank0 + c;
            int len  = lenR[d*NSEQ + rank];
            size_t cidx = ((size_t)d*KROW + 300 + m)*NSEQ + rank;
            float cold = actB_cur[cidx];
            float f  = sigmoidf_(g0);
            float i2 = sigmoidf_(g1);
            float cb = tanhf(g2);
            float cn = (s < len) ? (f*cold + i2*cb) : cold;
            actB_next[cidx] = cn;
            if (s == len - 1) {
                int ch = perm[d*NSEQ + rank];
                c_final[((size_t)d*NSEQ + ch)*M + m] = cn;
            }
        }
    }
}

__global__ void env_kernel(const float* __restrict__ l_states, const float* __restrict__ r_states,
                           const float* __restrict__ Wo, const float* __restrict__ Uo,
                           const float* __restrict__ bo,
                           float* __restrict__ env)
{
    __shared__ __align__(16) float l[M];
    __shared__ __align__(16) float r[M];
    const int i = blockIdx.x;
    const int tid = threadIdx.x;
    for (int m=tid; m<M; m+=blockDim.x){ l[m]=l_states[i*M+m]; r[m]=r_states[i*M+m]; }
    __syncthreads();
    for (int d=tid; d<D; d+=blockDim.x) {
        const float4* wo = reinterpret_cast<const float4*>(Wo + (size_t)d*M);
        const float4* uo = reinterpret_cast<const float4*>(Uo + (size_t)d*M);
        const float4* lv = reinterpret_cast<const float4*>(l);
        const float4* rv = reinterpret_cast<const float4*>(r);
        float acc = bo[d];
        #pragma unroll 5
        for (int q=0; q<M/4; ++q) {
            float4 a=wo[q], bv=lv[q], u=uo[q], rr=rv[q];
            acc += a.x*bv.x + a.y*bv.y + a.z*bv.z + a.w*bv.w;
            acc += u.x*rr.x + u.y*rr.y + u.z*rr.z + u.w*rr.w;
        }
        env[i*D + d] = tanhf(acc);
    }
}

__global__ void episode_kernel(const float* __restrict__ env, const int* __restrict__ target_y,
                               float* __restrict__ flags, float* __restrict__ losses)
{
    const int b = blockIdx.x;
    const int lane = threadIdx.x;
    const float* tgt = env + (size_t)(NSUP + b)*D;

    float tn = 0.f;
    for (int d=lane; d<D; d+=64){ float v=tgt[d]; tn += v*v; }
    for (int off=32; off; off>>=1) tn += __shfl_down(tn, off);
    tn = __shfl(tn, 0);

    float z[NW];
    for (int n=0; n<NW; ++n){
        const float* sup = env + (size_t)(b*NW + n)*D;
        float dot=0.f, sn=0.f;
        for (int d=lane; d<D; d+=64){ float sv=sup[d], tv=tgt[d]; dot+=sv*tv; sn+=sv*sv; }
        for (int off=32; off; off>>=1){ dot += __shfl_down(dot,off); sn += __shfl_down(sn,off); }
        dot = __shfl(dot,0); sn = __shfl(sn,0);
        float denom = fmaxf(sqrtf(sn)*sqrtf(tn), 1e-8f);
        z[n] = dot/denom*10.0f;
    }

    if (lane==0){
        float mx=z[0];
        for(int n=1;n<NW;n++) mx=fmaxf(mx,z[n]);
        float se=0.f; float p[NW];
        for(int n=0;n<NW;n++){ p[n]=expf(z[n]-mx); se+=p[n]; }
        for(int n=0;n<NW;n++) p[n]/=se;
        int am=0; float bv=p[0];
        for(int n=1;n<NW;n++) if(p[n]>bv){bv=p[n];am=n;}
        int y = target_y[b];
        flags[b] = (am==y)?1.0f:0.0f;
        float mx2=p[0]; for(int n=1;n<NW;n++) mx2=fmaxf(mx2,p[n]);
        float se2=0.f; for(int n=0;n<NW;n++) se2+=expf(p[n]-mx2);
        losses[b] = -(p[y]-mx2-logf(se2));
    }
}

__global__ void finalize_kernel(const float* __restrict__ flags, const float* __restrict__ losses,
                                float* __restrict__ out)
{
    const int lane = threadIdx.x; // 64 threads
    float f = flags[lane], l = losses[lane];
    for (int off=32; off; off>>=1){ f += __shfl_down(f,off); l += __shfl_down(l,off); }
    if (lane==0){ out[0] = f/(float)B; out[1] = l/(float)B; }
}

extern "C" void kernel_launch(void* const* d_in, const int* in_sizes, int n_in,
                              void* d_out, int out_size, void* d_ws, size_t ws_size,
                              hipStream_t stream) {
    const int*   sup_tok   = (const int*)d_in[0];
    const int*   tgt_tok   = (const int*)d_in[1];
    const int*   blank_sup = (const int*)d_in[2];
    const int*   blank_tgt = (const int*)d_in[3];
    const int*   target_y  = (const int*)d_in[4];
    const float* emb = (const float*)d_in[5];
    const float* WL  = (const float*)d_in[6];
    const float* UL  = (const float*)d_in[7];
    const float* bL  = (const float*)d_in[8];
    const float* WR  = (const float*)d_in[9];
    const float* UR  = (const float*)d_in[10];
    const float* bR  = (const float*)d_in[11];
    const float* Wo  = (const float*)d_in[12];
    const float* Uo  = (const float*)d_in[13];
    const float* bo  = (const float*)d_in[14];
    const float* c0L = (const float*)d_in[15];
    const float* c0R = (const float*)d_in[16];

    const size_t ACTSZ = (size_t)2*KROW*NSEQ;           // 614400 floats
    float* ws_f = (float*)d_ws;
    float* actB0   = ws_f;
    float* actB1   = actB0 + ACTSZ;
    float* c_final = actB1 + ACTSZ;                     // [2*384*500]
    float* env     = c_final + 2*NSEQ*M;                // [384*300]
    float* flags   = env + NSEQ*D;                      // [64]
    float* losses  = flags + B;                         // [64]
    int*   perm    = (int*)(losses + B);                // [2*384]
    int*   lenR    = perm + 2*NSEQ;                     // [2*384]
    int*   tmax    = lenR + 2*NSEQ;                     // [16]

    init_kernel<<<(2*M*NSEQ + 255)/256, 256, 0, stream>>>(c0L, c0R, actB0, c_final);
    sort_kernel<<<1, NSEQ, 0, stream>>>(blank_sup, blank_tgt, perm, lenR, tmax);

    // prologue: gather x for step 0 into actB0 (compute blocks no-op at s=-1)
    step_kernel<<<NCOMP + NGATH, 256, 0, stream>>>(-1, actB1, actB0, c_final,
                                                   WL, UL, bL, WR, UR, bR,
                                                   perm, lenR, tmax, sup_tok, tgt_tok, emb);
    for (int s = 0; s < NSTEP; ++s) {
        float* cur  = (s & 1) ? actB1 : actB0;
        float* next = (s & 1) ? actB0 : actB1;
        step_kernel<<<NCOMP + NGATH, 256, 0, stream>>>(s, cur, next, c_final,
                                                       WL, UL, bL, WR, UR, bR,
                                                       perm, lenR, tmax, sup_tok, tgt_tok, emb);
    }

    env_kernel<<<NSEQ, 256, 0, stream>>>(c_final, c_final + NSEQ*M, Wo, Uo, bo, env);
    episode_kernel<<<B, 64, 0, stream>>>(env, target_y, flags, losses);
    finalize_kernel<<<1, 64, 0, stream>>>(flags, losses, (float*)d_out);
}